// Round 3
// baseline (514.147 us; speedup 1.0000x reference)
//
#include <hip/hip_runtime.h>
#include <hip/hip_cooperative_groups.h>

namespace cg = cooperative_groups;

#define N_NODES 40000
#define N_EDGES 160000
#define N_FEATS 74
#define DD 1024
#define HD 3072
#define N_GRAPHS 800
#define NBLK 768
#define NTHR 256

__device__ __forceinline__ float waveReduceSum(float v) {
    #pragma unroll
    for (int off = 32; off > 0; off >>= 1)
        v += __shfl_down(v, off, 64);
    return v;
}
__device__ __forceinline__ float lrelu02(float x) { return x > 0.f ? x : 0.2f * x; }

__global__ __launch_bounds__(NTHR, 4) void kFused(
    const float* __restrict__ feats, const float* __restrict__ W,
    const float* __restrict__ al, const float* __restrict__ ar,
    const float* __restrict__ bias, const float* __restrict__ W1,
    const float* __restrict__ b1, const float* __restrict__ W2,
    const float* __restrict__ b2, const int* __restrict__ src,
    const int* __restrict__ dst, const int* __restrict__ gids,
    float* __restrict__ ws, float* __restrict__ y)
{
    cg::grid_group grid = cg::this_grid();

    // workspace layout (floats; el4 at 4096 keeps float4 arrays 16B-aligned)
    float* v   = ws;                       // 3072
    float* wl9 = ws + 3072;                // 672 (666 used)
    float* c0  = ws + 3744;                // 1
    float* bgv = ws + 3745;                // 1
    float* el4 = ws + 4096;                // N*4
    float* er4 = el4 + N_NODES * 4;        // N*4
    float* hv4 = er4 + N_NODES * 4;        // N*4
    float* nd  = hv4 + N_NODES * 4;        // N*8 : [num0..2,_,den0..2,_]
    float* ygr = nd + N_NODES * 8;         // 800
    int*   cnt = (int*)(ygr + N_GRAPHS);   // 800

    const int tid = blockIdx.x * NTHR + threadIdx.x;
    const int nthreads = gridDim.x * NTHR;
    const int wave = tid >> 6, lane = tid & 63;
    const int nwaves = nthreads >> 6;

    __shared__ float lw[N_FEATS * 9];

    // ---------- P0: zero accumulators; v = W1@W2; c0 = b1.W2+b2; wl9 L/R ----------
    for (int i = tid; i < N_NODES * 8; i += nthreads) nd[i] = 0.f;
    for (int i = tid; i < N_GRAPHS; i += nthreads) { ygr[i] = 0.f; cnt[i] = 0; }
    for (int w = wave; w < HD + 1 + N_FEATS * 3; w += nwaves) {
        if (w < HD) {
            const float* row = W1 + (size_t)w * DD;
            float acc = 0.f;
            for (int t = lane; t < DD; t += 64) acc += row[t] * W2[t];
            acc = waveReduceSum(acc);
            if (!lane) v[w] = acc;
        } else if (w == HD) {
            float acc = 0.f;
            for (int t = lane; t < DD; t += 64) acc += b1[t] * W2[t];
            acc = waveReduceSum(acc);
            if (!lane) *c0 = acc + b2[0];
        } else {
            int w2 = w - HD - 1;
            int f = w2 / 3, h = w2 - f * 3;
            const float* rw = W + (size_t)f * HD + h * DD;
            const float* pl = al + h * DD;
            const float* pr = ar + h * DD;
            float aL = 0.f, aR = 0.f;
            for (int t = lane; t < DD; t += 64) {
                float x = rw[t];
                aL += x * pl[t]; aR += x * pr[t];
            }
            aL = waveReduceSum(aL); aR = waveReduceSum(aR);
            if (!lane) { wl9[f * 9 + h] = aL; wl9[f * 9 + 3 + h] = aR; }
        }
    }
    grid.sync();

    // ---------- P1: wl9 V column (needs v); bgv = bias_gat . v ----------
    for (int w = wave; w < N_FEATS * 3 + 1; w += nwaves) {
        if (w < N_FEATS * 3) {
            int f = w / 3, h = w - f * 3;
            const float* rw = W + (size_t)f * HD + h * DD;
            const float* pv = v + h * DD;
            float aV = 0.f;
            for (int t = lane; t < DD; t += 64) aV += rw[t] * pv[t];
            aV = waveReduceSum(aV);
            if (!lane) wl9[f * 9 + 6 + h] = aV;
        } else {
            float acc = 0.f;
            for (int t = lane; t < HD; t += 64) acc += bias[t] * v[t];
            acc = waveReduceSum(acc);
            if (!lane) *bgv = acc;
        }
    }
    grid.sync();

    // ---------- P2: node projections el/er/hv = feats @ [Wl|Wr|Wv] ----------
    for (int i = threadIdx.x; i < N_FEATS * 9; i += NTHR) lw[i] = wl9[i];
    __syncthreads();
    for (int i = tid; i < N_NODES; i += nthreads) {
        const float* row = feats + (size_t)i * N_FEATS;
        float a0=0,a1=0,a2=0,a3=0,a4=0,a5=0,a6=0,a7=0,a8=0;
        #pragma unroll 4
        for (int f = 0; f < N_FEATS; f += 2) {
            float2 x2 = *(const float2*)(row + f);
            const float* w0 = lw + f * 9;
            a0 += x2.x * w0[0]; a1 += x2.x * w0[1]; a2 += x2.x * w0[2];
            a3 += x2.x * w0[3]; a4 += x2.x * w0[4]; a5 += x2.x * w0[5];
            a6 += x2.x * w0[6]; a7 += x2.x * w0[7]; a8 += x2.x * w0[8];
            const float* w1 = w0 + 9;
            a0 += x2.y * w1[0]; a1 += x2.y * w1[1]; a2 += x2.y * w1[2];
            a3 += x2.y * w1[3]; a4 += x2.y * w1[4]; a5 += x2.y * w1[5];
            a6 += x2.y * w1[6]; a7 += x2.y * w1[7]; a8 += x2.y * w1[8];
        }
        ((float4*)el4)[i] = make_float4(a0, a1, a2, 0.f);
        ((float4*)er4)[i] = make_float4(a3, a4, a5, 0.f);
        ((float4*)hv4)[i] = make_float4(a6, a7, a8, 0.f);
        atomicAdd(&cnt[gids[i]], 1);
    }
    grid.sync();

    // ---------- P3: single edge pass: num += ex*hv[src], den += ex ----------
    for (int e = tid; e < N_EDGES; e += nthreads) {
        int s = src[e], d = dst[e];
        float4 L = ((const float4*)el4)[s];
        float4 R = ((const float4*)er4)[d];
        float4 V = ((const float4*)hv4)[s];
        float e0 = expf(lrelu02(L.x + R.x));
        float e1 = expf(lrelu02(L.y + R.y));
        float e2 = expf(lrelu02(L.z + R.z));
        float* p = nd + (size_t)d * 8;
        atomicAdd(p + 0, e0 * V.x);
        atomicAdd(p + 1, e1 * V.y);
        atomicAdd(p + 2, e2 * V.z);
        atomicAdd(p + 4, e0);
        atomicAdd(p + 5, e1);
        atomicAdd(p + 6, e2);
    }
    grid.sync();

    // ---------- P4: per-node combine + pool into per-graph bins ----------
    for (int i = tid; i < N_NODES; i += nthreads) {
        float4 num = ((const float4*)nd)[i * 2];
        float4 den = ((const float4*)nd)[i * 2 + 1];
        float c = 0.f;
        if (den.x > 0.f) c = num.x / den.x + num.y / den.y + num.z / den.z;
        atomicAdd(&ygr[gids[i]], c);
    }
    grid.sync();

    // ---------- P5: finalize ----------
    for (int g = tid; g < N_GRAPHS; g += nthreads) {
        int cg_ = cnt[g];
        float cc = (float)(cg_ > 0 ? cg_ : 1);
        y[g] = ygr[g] / cc + bgv[0] + c0[0];
    }
}

extern "C" void kernel_launch(void* const* d_in, const int* in_sizes, int n_in,
                              void* d_out, int out_size, void* d_ws, size_t ws_size,
                              hipStream_t stream) {
    const float* feats = (const float*)d_in[0];
    const float* W     = (const float*)d_in[1];
    const float* al    = (const float*)d_in[2];
    const float* ar    = (const float*)d_in[3];
    const float* bias  = (const float*)d_in[4];
    const float* W1    = (const float*)d_in[5];
    const float* b1    = (const float*)d_in[6];
    const float* W2    = (const float*)d_in[7];
    const float* b2    = (const float*)d_in[8];
    const int*   src   = (const int*)d_in[9];
    const int*   dst   = (const int*)d_in[10];
    const int*   gids  = (const int*)d_in[11];
    float* ws = (float*)d_ws;
    float* y  = (float*)d_out;

    void* args[] = { (void*)&feats, (void*)&W, (void*)&al, (void*)&ar,
                     (void*)&bias, (void*)&W1, (void*)&b1, (void*)&W2,
                     (void*)&b2, (void*)&src, (void*)&dst, (void*)&gids,
                     (void*)&ws, (void*)&y };
    hipLaunchCooperativeKernel((void*)kFused, dim3(NBLK), dim3(NTHR), args, 0, stream);
}

// Round 4
// 92.087 us; speedup vs baseline: 5.5833x; 5.5833x over previous
//
#include <hip/hip_runtime.h>

#define N_NODES 40000
#define N_EDGES 160000
#define N_FEATS 74
#define DD 1024
#define HD 3072
#define N_GRAPHS 800

__device__ __forceinline__ float waveReduceSum(float v) {
    #pragma unroll
    for (int off = 32; off > 0; off >>= 1)
        v += __shfl_down(v, off, 64);
    return v;
}
__device__ __forceinline__ float lrelu02(float x) { return x > 0.f ? x : 0.2f * x; }

// ---- K1: v = W1@W2 (3072), c0 = b1.W2+b2, wl9 L/R columns (don't need v) ----
__global__ void kV(const float* __restrict__ W1, const float* __restrict__ W2,
                   const float* __restrict__ b1, const float* __restrict__ b2,
                   const float* __restrict__ W, const float* __restrict__ al,
                   const float* __restrict__ ar,
                   float* __restrict__ v, float* __restrict__ c0,
                   float* __restrict__ wl9) {
    int w = blockIdx.x * 4 + (threadIdx.x >> 6);
    int lane = threadIdx.x & 63;
    if (w < HD) {
        const float* row = W1 + (size_t)w * DD;
        float acc = 0.f;
        for (int t = lane; t < DD; t += 64) acc += row[t] * W2[t];
        acc = waveReduceSum(acc);
        if (!lane) v[w] = acc;
    } else if (w == HD) {
        float acc = 0.f;
        for (int t = lane; t < DD; t += 64) acc += b1[t] * W2[t];
        acc = waveReduceSum(acc);
        if (!lane) *c0 = acc + b2[0];
    } else if (w < HD + 1 + N_FEATS * 3) {
        int w2 = w - HD - 1;
        int f = w2 / 3, h = w2 - f * 3;
        const float* rw = W + (size_t)f * HD + h * DD;
        const float* pl = al + h * DD;
        const float* pr = ar + h * DD;
        float aL = 0.f, aR = 0.f;
        for (int t = lane; t < DD; t += 64) {
            float x = rw[t];
            aL += x * pl[t]; aR += x * pr[t];
        }
        aL = waveReduceSum(aL); aR = waveReduceSum(aR);
        if (!lane) { wl9[f * 9 + h] = aL; wl9[f * 9 + 3 + h] = aR; }
    }
}

// ---- K2: wl9 V column = W_col . v ; bgv = bias_gat . v (need v) ----
__global__ void kProj(const float* __restrict__ W, const float* __restrict__ v,
                      const float* __restrict__ bias,
                      float* __restrict__ wl9, float* __restrict__ bgv) {
    int w = blockIdx.x * 4 + (threadIdx.x >> 6);
    int lane = threadIdx.x & 63;
    if (w < N_FEATS * 3) {
        int f = w / 3, h = w - f * 3;
        const float* rw = W + (size_t)f * HD + h * DD;
        const float* pv = v + h * DD;
        float aV = 0.f;
        for (int t = lane; t < DD; t += 64) aV += rw[t] * pv[t];
        aV = waveReduceSum(aV);
        if (!lane) wl9[f * 9 + 6 + h] = aV;
    } else if (w == N_FEATS * 3) {
        float acc = 0.f;
        for (int t = lane; t < HD; t += 64) acc += bias[t] * v[t];
        acc = waveReduceSum(acc);
        if (!lane) *bgv = acc;
    }
}

// ---- K3: node projections; sn = [el|hv] packed 32B; er separate; zero nd ----
__global__ __launch_bounds__(256) void kNode(const float* __restrict__ feats,
                      const float* __restrict__ wl9,
                      float4* __restrict__ sn4,   // [N][2]: {el0..2,_},{hv0..2,_}
                      float4* __restrict__ er4,   // [N]
                      float4* __restrict__ nd4) { // [N][2] zeroed here
    __shared__ float tile[256 * 75];
    __shared__ float lw[N_FEATS * 9];
    int t = threadIdx.x;
    int base = blockIdx.x * 256;
    int nvalid = min(256, N_NODES - base);
    for (int i = t; i < N_FEATS * 9; i += 256) lw[i] = wl9[i];
    int total = nvalid * N_FEATS;
    const float* srcp = feats + (size_t)base * N_FEATS;
    for (int i = t; i < total; i += 256) {
        int node = i / N_FEATS;
        int f = i - node * N_FEATS;
        tile[node * 75 + f] = srcp[i];
    }
    __syncthreads();
    if (t < nvalid) {
        float a0=0,a1=0,a2=0,a3=0,a4=0,a5=0,a6=0,a7=0,a8=0;
        const float* row = tile + t * 75;
        #pragma unroll 2
        for (int f = 0; f < N_FEATS; ++f) {
            float x = row[f];
            const float* wp = lw + f * 9;
            a0 += x * wp[0]; a1 += x * wp[1]; a2 += x * wp[2];
            a3 += x * wp[3]; a4 += x * wp[4]; a5 += x * wp[5];
            a6 += x * wp[6]; a7 += x * wp[7]; a8 += x * wp[8];
        }
        int i = base + t;
        sn4[i * 2]     = make_float4(a0, a1, a2, 0.f);  // el
        sn4[i * 2 + 1] = make_float4(a6, a7, a8, 0.f);  // hv
        er4[i]         = make_float4(a3, a4, a5, 0.f);
        nd4[i * 2]     = make_float4(0.f, 0.f, 0.f, 0.f);
        nd4[i * 2 + 1] = make_float4(0.f, 0.f, 0.f, 0.f);
    }
}

// ---- K4: single edge pass: nd[d] += {ex*hv, ex} ----
__global__ void kEdge(const int* __restrict__ src, const int* __restrict__ dst,
                      const float4* __restrict__ sn4, const float4* __restrict__ er4,
                      float* __restrict__ nd) {
    int e = blockIdx.x * blockDim.x + threadIdx.x;
    if (e >= N_EDGES) return;
    int s = src[e], d = dst[e];
    float4 L = sn4[s * 2];
    float4 V = sn4[s * 2 + 1];
    float4 R = er4[d];
    float e0 = expf(lrelu02(L.x + R.x));
    float e1 = expf(lrelu02(L.y + R.y));
    float e2 = expf(lrelu02(L.z + R.z));
    float* p = nd + (size_t)d * 8;
    atomicAdd(p + 0, e0 * V.x);
    atomicAdd(p + 1, e1 * V.y);
    atomicAdd(p + 2, e2 * V.z);
    atomicAdd(p + 4, e0);
    atomicAdd(p + 5, e1);
    atomicAdd(p + 6, e2);
}

// ---- K5: one wave per graph: y[g] = mean_i(sum_h num/den) + bgv + c0 ----
__global__ void kPoolFinal(const float4* __restrict__ nd4,
                           const float* __restrict__ bgv, const float* __restrict__ c0,
                           float* __restrict__ y) {
    int g = blockIdx.x * 4 + (threadIdx.x >> 6);
    int lane = threadIdx.x & 63;
    if (g >= N_GRAPHS) return;
    float c = 0.f;
    if (lane < 50) {
        int i = g * 50 + lane;
        float4 num = nd4[i * 2];
        float4 den = nd4[i * 2 + 1];
        if (den.x > 0.f) c = num.x / den.x + num.y / den.y + num.z / den.z;
    }
    c = waveReduceSum(c);
    if (!lane) y[g] = c * (1.f / 50.f) + bgv[0] + c0[0];
}

extern "C" void kernel_launch(void* const* d_in, const int* in_sizes, int n_in,
                              void* d_out, int out_size, void* d_ws, size_t ws_size,
                              hipStream_t stream) {
    const float* feats = (const float*)d_in[0];
    const float* W     = (const float*)d_in[1];
    const float* al    = (const float*)d_in[2];
    const float* ar    = (const float*)d_in[3];
    const float* bias  = (const float*)d_in[4];
    const float* W1    = (const float*)d_in[5];
    const float* b1    = (const float*)d_in[6];
    const float* W2    = (const float*)d_in[7];
    const float* b2    = (const float*)d_in[8];
    const int*   src   = (const int*)d_in[9];
    const int*   dst   = (const int*)d_in[10];

    float* ws  = (float*)d_ws;
    float* v   = ws;                      // 3072
    float* wl9 = ws + 3072;               // 672
    float* c0  = ws + 3744;               // 1
    float* bgv = ws + 3745;               // 1
    float* sn  = ws + 4096;               // N*8 (16B-aligned)
    float* er  = sn + N_NODES * 8;        // N*4
    float* nd  = er + N_NODES * 4;        // N*8
    float* y   = (float*)d_out;

    hipLaunchKernelGGL(kV, dim3((HD + 1 + N_FEATS * 3 + 3) / 4), dim3(256), 0, stream,
                       W1, W2, b1, b2, W, al, ar, v, c0, wl9);
    hipLaunchKernelGGL(kProj, dim3((N_FEATS * 3 + 1 + 3) / 4), dim3(256), 0, stream,
                       W, v, bias, wl9, bgv);
    hipLaunchKernelGGL(kNode, dim3((N_NODES + 255) / 256), dim3(256), 0, stream,
                       feats, wl9, (float4*)sn, (float4*)er, (float4*)nd);
    hipLaunchKernelGGL(kEdge, dim3((N_EDGES + 255) / 256), dim3(256), 0, stream,
                       src, dst, (const float4*)sn, (const float4*)er, nd);
    hipLaunchKernelGGL(kPoolFinal, dim3((N_GRAPHS + 3) / 4), dim3(256), 0, stream,
                       (const float4*)nd, bgv, c0, y);
}